// Round 6
// baseline (558.961 us; speedup 1.0000x reference)
//
#include <hip/hip_runtime.h>

#define NBATCH 32
#define NDIM 512

// ---- DPP cross-lane primitives (VALU-speed; no LDS, no barriers) ----

template <int CTRL, int RMASK>
__device__ __forceinline__ float dpp_add(float x) {
  int t = __builtin_amdgcn_update_dpp(0, __float_as_int(x), CTRL, RMASK, 0xf,
                                      false);
  return x + __int_as_float(t);
}

// wave64 inclusive prefix sum
__device__ __forceinline__ float prefix_inc(float x) {
  x = dpp_add<0x111, 0xf>(x);  // row_shr:1
  x = dpp_add<0x112, 0xf>(x);  // row_shr:2
  x = dpp_add<0x114, 0xf>(x);  // row_shr:4
  x = dpp_add<0x118, 0xf>(x);  // row_shr:8
  x = dpp_add<0x142, 0xa>(x);  // row_bcast:15 -> rows 1,3
  x = dpp_add<0x143, 0xc>(x);  // row_bcast:31 -> rows 2,3
  return x;
}

// shift one lane up (lane i gets lane i-1); lane 0 receives `fill`
__device__ __forceinline__ float wave_shr1(float x, float fill) {
  return __int_as_float(__builtin_amdgcn_update_dpp(
      __float_as_int(fill), __float_as_int(x), 0x138 /*wave_shr:1*/, 0xf, 0xf,
      false));
}

// one step of the wave64 inclusive affine-composition scan.
// Lane's (A,B) := later segment; incoming dpp (Ae,Be) := earlier segment.
// Compose earlier-then-later: B = A*Be + B ; A = A*Ae. Identity = (1,0).
template <int CTRL, int RMASK>
__device__ __forceinline__ void aff_step(float& A, float& B) {
  float Ae = __int_as_float(__builtin_amdgcn_update_dpp(
      __float_as_int(1.0f), __float_as_int(A), CTRL, RMASK, 0xf, false));
  float Be = __int_as_float(__builtin_amdgcn_update_dpp(
      0, __float_as_int(B), CTRL, RMASK, 0xf, false));
  B = fmaf(A, Be, B);
  A = A * Ae;
}

// One wave per batch element; lane i owns columns [8i, 8i+8).
// Per row:
//  1. DPP prefix scans of fut and c2*w give mfm suffix mass R and the
//     linear guess u0 (exact through the exhausted regime, slope==1 there).
//  2. Sweep 1: true-branch evaluation of each lane's 8-column map from u0,
//     recording per-column slopes a_k in {1, 1-c2, 1-c1, 1-c1-c2}.
//     Lane map is locally affine: M(v) = out + A*(v - u0), A = prod a_k.
//  3. Affine-composition DPP scan of (A, B=out-A*u0) yields every lane's
//     entry e_i exactly (where sweep-1 branch pattern == true pattern;
//     mismatches are frontier-local, bounded, clamped, and contracted by
//     the final sweep since all slopes <= 1).
//  4. Final true-branch sweep from e_i emits p, updates w, and computes the
//     NEXT row's fut/t8 in the same pass (scan inputs ready at loop head).
// No LDS, no barriers; rows chain only through registers.
__global__ __launch_bounds__(64, 1)
void sb_kernel(const float* __restrict__ x, const float* __restrict__ xm,
               float* __restrict__ out) {
  const int lane = threadIdx.x;
  const size_t base = (size_t)blockIdx.x * NDIM * NDIM + lane * 8;
  const float* xb = x + base;
  const float* mb = xm + base;
  float* ob = out + base;

  float w8[8], fu[8], t8[8];
#pragma unroll
  for (int k = 0; k < 8; ++k) w8[k] = 1.0f;

  // row 0 load + prep
  float4 xA = *(const float4*)(xb);
  float4 xB = *(const float4*)(xb + 4);
  float4 mA = *(const float4*)(mb);
  float4 mB = *(const float4*)(mb + 4);
  float c1c[8], c2c[8], oc2[8];
  {
    float xr[8] = {xA.x, xA.y, xA.z, xA.w, xB.x, xB.y, xB.z, xB.w};
    float mr[8] = {mA.x, mA.y, mA.z, mA.w, mB.x, mB.y, mB.z, mB.w};
#pragma unroll
    for (int k = 0; k < 8; ++k) {
      float bb = __builtin_amdgcn_rcpf(1.0f + __expf(-xr[k]));
      c2c[k] = mr[k] * bb;
      c1c[k] = mr[k] - c2c[k];
      oc2[k] = 1.0f - c2c[k];
      fu[k] = fmaxf(w8[k] - (1.0f - mr[k]), 0.0f);
      t8[k] = c2c[k] * w8[k];
    }
  }

#pragma unroll 1
  for (int m = 0; m < NDIM; ++m) {
    // issue next row's loads (clamped on last iter; result unused there)
    const size_t nro = (size_t)((m + 1 < NDIM) ? m + 1 : m) * NDIM;
    xA = *(const float4*)(xb + nro);
    xB = *(const float4*)(xb + nro + 4);
    mA = *(const float4*)(mb + nro);
    mB = *(const float4*)(mb + nro + 4);

    // ---- scans (fu/t8 were produced by the previous iteration's tail) ----
    float S = ((fu[0] + fu[1]) + (fu[2] + fu[3])) +
              ((fu[4] + fu[5]) + (fu[6] + fu[7]));
    float sa = ((t8[0] + t8[1]) + (t8[2] + t8[3])) +
               ((t8[4] + t8[5]) + (t8[6] + t8[7]));
    float PS = prefix_inc(S);
    float PA = prefix_inc(sa);
    float T = __int_as_float(__builtin_amdgcn_readlane(__float_as_int(PS), 63));
    float R = T - PS;  // future mass strictly after this lane

    // tree-structured within-lane suffix for mfm (depth ~4, not serial 8)
    float s23 = fu[2] + fu[3], s45 = fu[4] + fu[5], s67 = fu[6] + fu[7];
    float s4567 = s45 + s67;
    float mfm[8], nc1m[8];
    mfm[7] = R;
    mfm[6] = R + fu[7];
    mfm[5] = R + s67;
    mfm[4] = mfm[5] + fu[5];
    mfm[3] = R + s4567;
    mfm[2] = mfm[3] + fu[3];
    mfm[1] = mfm[3] + s23;
    mfm[0] = mfm[1] + fu[1];
#pragma unroll
    for (int k = 0; k < 8; ++k) nc1m[k] = -c1c[k] * mfm[k];

    const float uin = fmaxf(1.0f - (PA - sa), 0.0f);  // linear guess

    // ---- sweep 1: true branches from uin, record slopes ----
    float u = uin;
    float aa[8];
#pragma unroll
    for (int k = 0; k < 8; ++k) {
      float gf = fmaf(c1c[k], u, nc1m[k]);
      float g = fmaxf(gf, 0.0f);
      float U = fminf(u, w8[k]);
      float a = (w8[k] < u) ? 1.0f : oc2[k];  // U-branch slope part
      a = (gf > 0.0f) ? (a - c1c[k]) : a;     // g-branch slope part
      aa[k] = a;
      u = fmaf(-c2c[k], U, u) - g;
    }
    float A = ((aa[0] * aa[1]) * (aa[2] * aa[3])) *
              ((aa[4] * aa[5]) * (aa[6] * aa[7]));
    float Bv = fmaf(-A, uin, u);  // M(v) = A*v + Bv

    // ---- affine-composition scan + exclusive entry ----
    aff_step<0x111, 0xf>(A, Bv);
    aff_step<0x112, 0xf>(A, Bv);
    aff_step<0x114, 0xf>(A, Bv);
    aff_step<0x118, 0xf>(A, Bv);
    aff_step<0x142, 0xa>(A, Bv);
    aff_step<0x143, 0xc>(A, Bv);
    float Aex = wave_shr1(A, 1.0f);
    float Bex = wave_shr1(Bv, 0.0f);
    float e = fminf(fmaxf(Aex + Bex, 0.0f), 1.0f);  // entry, clamped to [0,1]

    // ---- next row's x-only prep (independent; fills stall slots) ----
    float c1n[8], c2n[8], oc2n[8], omn[8];
    {
      float xr[8] = {xA.x, xA.y, xA.z, xA.w, xB.x, xB.y, xB.z, xB.w};
      float mr[8] = {mA.x, mA.y, mA.z, mA.w, mB.x, mB.y, mB.z, mB.w};
#pragma unroll
      for (int k = 0; k < 8; ++k) {
        float bb = __builtin_amdgcn_rcpf(1.0f + __expf(-xr[k]));
        c2n[k] = mr[k] * bb;
        c1n[k] = mr[k] - c2n[k];
        oc2n[k] = 1.0f - c2n[k];
        omn[k] = 1.0f - mr[k];
      }
    }

    // ---- final sweep: emit p, update w, build next row's scan inputs ----
    u = e;
    float pv[8];
#pragma unroll
    for (int k = 0; k < 8; ++k) {
      float g = fmaxf(fmaf(c1c[k], u, nc1m[k]), 0.0f);
      float U = fminf(u, w8[k]);
      float un = fmaf(-c2c[k], U, u) - g;
      float p = u - un;  // off the u-chain
      pv[k] = p;
      float wn = w8[k] - p;
      w8[k] = wn;
      fu[k] = fmaxf(wn - omn[k], 0.0f);  // next row's fut
      t8[k] = c2n[k] * wn;               // next row's c2*w
      u = un;
    }
    float* orow = ob + (size_t)m * NDIM;
    *(float4*)(orow) = make_float4(pv[0], pv[1], pv[2], pv[3]);
    *(float4*)(orow + 4) = make_float4(pv[4], pv[5], pv[6], pv[7]);

    // rotate next-row constants in
#pragma unroll
    for (int k = 0; k < 8; ++k) {
      c1c[k] = c1n[k];
      c2c[k] = c2n[k];
      oc2[k] = oc2n[k];
    }
  }
}

extern "C" void kernel_launch(void* const* d_in, const int* in_sizes, int n_in,
                              void* d_out, int out_size, void* d_ws, size_t ws_size,
                              hipStream_t stream) {
  const float* x = (const float*)d_in[0];
  const float* xmask = (const float*)d_in[1];
  float* out = (float*)d_out;
  (void)in_sizes; (void)n_in; (void)out_size; (void)d_ws; (void)ws_size;
  hipLaunchKernelGGL(sb_kernel, dim3(NBATCH), dim3(64), 0, stream, x, xmask, out);
}

// Round 7
// 494.460 us; speedup vs baseline: 1.1304x; 1.1304x over previous
//
#include <hip/hip_runtime.h>

#define NBATCH 32
#define NDIM 512

// ---- DPP cross-lane primitives (VALU-speed; no LDS, no barriers) ----

template <int CTRL, int RMASK>
__device__ __forceinline__ float dpp_add(float x) {
  int t = __builtin_amdgcn_update_dpp(0, __float_as_int(x), CTRL, RMASK, 0xf,
                                      false);
  return x + __int_as_float(t);
}

// wave64 inclusive prefix sum
__device__ __forceinline__ float prefix_inc(float x) {
  x = dpp_add<0x111, 0xf>(x);  // row_shr:1
  x = dpp_add<0x112, 0xf>(x);  // row_shr:2
  x = dpp_add<0x114, 0xf>(x);  // row_shr:4
  x = dpp_add<0x118, 0xf>(x);  // row_shr:8
  x = dpp_add<0x142, 0xa>(x);  // row_bcast:15 -> rows 1,3
  x = dpp_add<0x143, 0xc>(x);  // row_bcast:31 -> rows 2,3
  return x;
}

// shift one lane up (lane i gets lane i-1); lane 0 receives `fill`
__device__ __forceinline__ float wave_shr1(float x, float fill) {
  return __int_as_float(__builtin_amdgcn_update_dpp(
      __float_as_int(fill), __float_as_int(x), 0x138 /*wave_shr:1*/, 0xf, 0xf,
      false));
}

// one step of the wave64 inclusive affine-composition scan.
// Compose earlier-then-later: B = A*Be + B ; A = A*Ae. Identity = (1,0);
// lanes outside RMASK keep (A,B) via old-operand = identity.
template <int CTRL, int RMASK>
__device__ __forceinline__ void aff_step(float& A, float& B) {
  float Ae = __int_as_float(__builtin_amdgcn_update_dpp(
      __float_as_int(1.0f), __float_as_int(A), CTRL, RMASK, 0xf, false));
  float Be = __int_as_float(__builtin_amdgcn_update_dpp(
      0, __float_as_int(B), CTRL, RMASK, 0xf, false));
  B = fmaf(A, Be, B);
  A = A * Ae;
}

// One wave per batch element; lane i owns columns [8i, 8i+8).
// Algorithm identical to the previous round (linear guess -> true-branch
// sweep recording slopes -> wave affine-composition scan -> final sweep).
// NEW: distance-2 software prefetch with ping-pong register buffers, so the
// s_waitcnt for row r's data sits ~2 full row-bodies after its loads were
// issued (covers L2/L3/HBM latency; previously <1 body was exposed).
__global__ __launch_bounds__(64, 1)
void sb_kernel(const float* __restrict__ x, const float* __restrict__ xm,
               float* __restrict__ out) {
  const int lane = threadIdx.x;
  const size_t base = (size_t)blockIdx.x * NDIM * NDIM + lane * 8;
  const float* xb = x + base;
  const float* mb = xm + base;
  float* ob = out + base;

  float w8[8], fu[8], t8[8];
#pragma unroll
  for (int k = 0; k < 8; ++k) w8[k] = 1.0f;

  // ping-pong load buffers: A holds row 0, B holds row 1
  float4 axA = *(const float4*)(xb);
  float4 axB = *(const float4*)(xb + 4);
  float4 amA = *(const float4*)(mb);
  float4 amB = *(const float4*)(mb + 4);
  float4 bxA = *(const float4*)(xb + NDIM);
  float4 bxB = *(const float4*)(xb + NDIM + 4);
  float4 bmA = *(const float4*)(mb + NDIM);
  float4 bmB = *(const float4*)(mb + NDIM + 4);

  float c1c[8], c2c[8], oc2[8];
  {  // row-0 constants + row-0 scan inputs (w == 1)
    float xr[8] = {axA.x, axA.y, axA.z, axA.w, axB.x, axB.y, axB.z, axB.w};
    float mr[8] = {amA.x, amA.y, amA.z, amA.w, amB.x, amB.y, amB.z, amB.w};
#pragma unroll
    for (int k = 0; k < 8; ++k) {
      float bb = __builtin_amdgcn_rcpf(1.0f + __expf(-xr[k]));
      c2c[k] = mr[k] * bb;
      c1c[k] = mr[k] - c2c[k];
      oc2[k] = 1.0f - c2c[k];
      fu[k] = fmaxf(mr[k], 0.0f);
      t8[k] = c2c[k];
    }
  }

  // wb*: buffer to overwrite with row m+2; rb*: buffer holding row m+1
  auto row_body = [&](int m, float4& wxA, float4& wxB, float4& wmA, float4& wmB,
                      const float4& rxA, const float4& rxB, const float4& rmA,
                      const float4& rmB) {
    // issue row m+2 loads (clamped on the last two iters; results unused)
    const int nr = (m + 2 < NDIM) ? m + 2 : NDIM - 1;
    const size_t nro = (size_t)nr * NDIM;
    wxA = *(const float4*)(xb + nro);
    wxB = *(const float4*)(xb + nro + 4);
    wmA = *(const float4*)(mb + nro);
    wmB = *(const float4*)(mb + nro + 4);

    // ---- scans (fu/t8 were produced by the previous iteration's tail) ----
    float S = ((fu[0] + fu[1]) + (fu[2] + fu[3])) +
              ((fu[4] + fu[5]) + (fu[6] + fu[7]));
    float sa = ((t8[0] + t8[1]) + (t8[2] + t8[3])) +
               ((t8[4] + t8[5]) + (t8[6] + t8[7]));
    float PS = prefix_inc(S);
    float PA = prefix_inc(sa);
    float T = __int_as_float(__builtin_amdgcn_readlane(__float_as_int(PS), 63));
    float R = T - PS;  // future mass strictly after this lane

    // tree-structured within-lane suffix for mfm
    float s23 = fu[2] + fu[3], s45 = fu[4] + fu[5], s67 = fu[6] + fu[7];
    float s4567 = s45 + s67;
    float mfm[8], nc1m[8];
    mfm[7] = R;
    mfm[6] = R + fu[7];
    mfm[5] = R + s67;
    mfm[4] = mfm[5] + fu[5];
    mfm[3] = R + s4567;
    mfm[2] = mfm[3] + fu[3];
    mfm[1] = mfm[3] + s23;
    mfm[0] = mfm[1] + fu[1];
#pragma unroll
    for (int k = 0; k < 8; ++k) nc1m[k] = -c1c[k] * mfm[k];

    const float uin = fmaxf(1.0f - (PA - sa), 0.0f);  // linear guess

    // ---- sweep 1: true branches from uin, record slopes ----
    float u = uin;
    float aa[8];
#pragma unroll
    for (int k = 0; k < 8; ++k) {
      float gf = fmaf(c1c[k], u, nc1m[k]);
      float g = fmaxf(gf, 0.0f);
      float U = fminf(u, w8[k]);
      float a = (w8[k] < u) ? 1.0f : oc2[k];
      a = (gf > 0.0f) ? (a - c1c[k]) : a;
      aa[k] = a;
      u = fmaf(-c2c[k], U, u) - g;
    }
    float A = ((aa[0] * aa[1]) * (aa[2] * aa[3])) *
              ((aa[4] * aa[5]) * (aa[6] * aa[7]));
    float Bv = fmaf(-A, uin, u);  // lane map M(v) = A*v + Bv

    // ---- affine-composition scan + exclusive entry ----
    aff_step<0x111, 0xf>(A, Bv);
    aff_step<0x112, 0xf>(A, Bv);
    aff_step<0x114, 0xf>(A, Bv);
    aff_step<0x118, 0xf>(A, Bv);
    aff_step<0x142, 0xa>(A, Bv);
    aff_step<0x143, 0xc>(A, Bv);
    float Aex = wave_shr1(A, 1.0f);
    float Bex = wave_shr1(Bv, 0.0f);
    float e = fminf(fmaxf(Aex + Bex, 0.0f), 1.0f);  // entry, clamped

    // ---- row m+1 x-only prep (loaded a full iteration ago; no stall) ----
    float c1n[8], c2n[8], oc2n[8], omn[8];
    {
      float xr[8] = {rxA.x, rxA.y, rxA.z, rxA.w, rxB.x, rxB.y, rxB.z, rxB.w};
      float mr[8] = {rmA.x, rmA.y, rmA.z, rmA.w, rmB.x, rmB.y, rmB.z, rmB.w};
#pragma unroll
      for (int k = 0; k < 8; ++k) {
        float bb = __builtin_amdgcn_rcpf(1.0f + __expf(-xr[k]));
        c2n[k] = mr[k] * bb;
        c1n[k] = mr[k] - c2n[k];
        oc2n[k] = 1.0f - c2n[k];
        omn[k] = 1.0f - mr[k];
      }
    }

    // ---- final sweep: emit p, update w, build next row's scan inputs ----
    u = e;
    float pv[8];
#pragma unroll
    for (int k = 0; k < 8; ++k) {
      float g = fmaxf(fmaf(c1c[k], u, nc1m[k]), 0.0f);
      float U = fminf(u, w8[k]);
      float un = fmaf(-c2c[k], U, u) - g;
      float p = u - un;  // off the u-chain
      pv[k] = p;
      float wn = w8[k] - p;
      w8[k] = wn;
      fu[k] = fmaxf(wn - omn[k], 0.0f);
      t8[k] = c2n[k] * wn;
      u = un;
    }
    float* orow = ob + (size_t)m * NDIM;
    *(float4*)(orow) = make_float4(pv[0], pv[1], pv[2], pv[3]);
    *(float4*)(orow + 4) = make_float4(pv[4], pv[5], pv[6], pv[7]);

#pragma unroll
    for (int k = 0; k < 8; ++k) {
      c1c[k] = c1n[k];
      c2c[k] = c2n[k];
      oc2[k] = oc2n[k];
    }
  };

#pragma unroll 1
  for (int m = 0; m < NDIM; m += 2) {
    row_body(m, axA, axB, amA, amB, bxA, bxB, bmA, bmB);
    row_body(m + 1, bxA, bxB, bmA, bmB, axA, axB, amA, amB);
  }
}

extern "C" void kernel_launch(void* const* d_in, const int* in_sizes, int n_in,
                              void* d_out, int out_size, void* d_ws, size_t ws_size,
                              hipStream_t stream) {
  const float* x = (const float*)d_in[0];
  const float* xmask = (const float*)d_in[1];
  float* out = (float*)d_out;
  (void)in_sizes; (void)n_in; (void)out_size; (void)d_ws; (void)ws_size;
  hipLaunchKernelGGL(sb_kernel, dim3(NBATCH), dim3(64), 0, stream, x, xmask, out);
}